// Round 1
// baseline (2114.708 us; speedup 1.0000x reference)
//
#include <hip/hip_runtime.h>
#include <hip/hip_bf16.h>

// ---------------- problem constants ----------------
#define BATCH   512
#define NUM_ENT 100000
#define EDIM    200
#define OCH     32          // conv out channels
#define OH      8
#define OW      18
#define FCK     4608        // 32*8*18
#define EPSV    1e-5f

// ---------------- ws layout (floats) ----------------
#define WS0   0        // [2]   bn0: mean, rs*g0
#define BN1   8        // [64]  bn1: sum/sumsq -> scale/shift
#define BN2   96       // [400] bn2: scale[200], shift[200]
#define Y2OFF 512      // [512*200]
#define YCOFF 103424   // [512*32*8*18]

__device__ __forceinline__ float sigf(float x) {
    return 1.0f / (1.0f + __expf(-x));
}

// k1: bn0 stats over gathered embeddings; zero bn1/bn2 accumulators
__global__ __launch_bounds__(256) void k1_bn0(const int* __restrict__ e1,
                                              const float* __restrict__ emb,
                                              const float* __restrict__ g0,
                                              float* __restrict__ ws) {
    __shared__ float red[256], red2[256];
    int tid = threadIdx.x;
    for (int i = tid; i < 512; i += 256) ws[i] = 0.0f;   // zero stats region
    __syncthreads();
    float s = 0.f, s2 = 0.f;
    for (int i = tid; i < BATCH * EDIM; i += 256) {
        int b = i / EDIM;
        int k = i - b * EDIM;
        float v = emb[(size_t)e1[b] * EDIM + k];
        s += v; s2 += v * v;
    }
    red[tid] = s; red2[tid] = s2;
    __syncthreads();
    for (int off = 128; off; off >>= 1) {
        if (tid < off) { red[tid] += red[tid + off]; red2[tid] += red2[tid + off]; }
        __syncthreads();
    }
    if (tid == 0) {
        const float inv = 1.0f / (BATCH * EDIM);
        float m = red[0] * inv;
        float var = red2[0] * inv - m * m;
        ws[WS0 + 0] = m;
        ws[WS0 + 1] = rsqrtf(var + EPSV) * g0[0];
    }
}

// k2: relation-indexed 3x3 conv on bn0-normalized x; atomic bn1 stats
__global__ __launch_bounds__(256) void k2_conv(const int* __restrict__ e1,
                                               const int* __restrict__ rel,
                                               const float* __restrict__ emb,
                                               const float* __restrict__ cw,
                                               const float* __restrict__ cb,
                                               const float* __restrict__ b0,
                                               float* __restrict__ ws) {
    __shared__ float xs[EDIM];
    __shared__ float wsh[OCH * 9];
    __shared__ float bsh[OCH];
    int b = blockIdx.x, tid = threadIdx.x;
    float m = ws[WS0 + 0], s = ws[WS0 + 1], b0v = b0[0];
    int r = rel[b];
    if (tid < EDIM) xs[tid] = fmaf(emb[(size_t)e1[b] * EDIM + tid] - m, s, b0v);
    for (int i = tid; i < OCH * 9; i += 256) wsh[i] = cw[(size_t)r * OCH * 9 + i];
    if (tid < OCH) bsh[tid] = cb[r * OCH + tid];
    __syncthreads();
    int o = tid >> 3, h = tid & 7;   // 32 channels x 8 rows
    float w0 = wsh[o*9+0], w1 = wsh[o*9+1], w2 = wsh[o*9+2];
    float w3 = wsh[o*9+3], w4 = wsh[o*9+4], w5 = wsh[o*9+5];
    float w6 = wsh[o*9+6], w7 = wsh[o*9+7], w8 = wsh[o*9+8];
    float bias = bsh[o];
    float* yout = ws + YCOFF + ((size_t)b * OCH + o) * (OH * OW) + h * OW;
    const float* r0 = &xs[(h + 0) * 20];
    const float* r1 = &xs[(h + 1) * 20];
    const float* r2 = &xs[(h + 2) * 20];
    float ls = 0.f, ls2 = 0.f;
    #pragma unroll
    for (int wd = 0; wd < OW; wd++) {
        float acc = bias;
        acc = fmaf(r0[wd+0], w0, acc); acc = fmaf(r0[wd+1], w1, acc); acc = fmaf(r0[wd+2], w2, acc);
        acc = fmaf(r1[wd+0], w3, acc); acc = fmaf(r1[wd+1], w4, acc); acc = fmaf(r1[wd+2], w5, acc);
        acc = fmaf(r2[wd+0], w6, acc); acc = fmaf(r2[wd+1], w7, acc); acc = fmaf(r2[wd+2], w8, acc);
        yout[wd] = acc;
        ls += acc; ls2 += acc * acc;
    }
    atomicAdd(&ws[BN1 + o], ls);
    atomicAdd(&ws[BN1 + 32 + o], ls2);
}

// k3: finalize bn1 (sum/sumsq -> scale/shift); init y2 with fc_b
__global__ __launch_bounds__(256) void k3_prep(const float* __restrict__ g1,
                                               const float* __restrict__ b1,
                                               const float* __restrict__ fcb,
                                               float* __restrict__ ws) {
    int gid = blockIdx.x, tid = threadIdx.x;
    if (gid == 0) {
        if (tid < OCH) {
            const float inv = 1.0f / (BATCH * OH * OW);
            float sm = ws[BN1 + tid], sq = ws[BN1 + 32 + tid];
            float m = sm * inv;
            float var = sq * inv - m * m;
            float a = rsqrtf(var + EPSV) * g1[tid];
            ws[BN1 + tid] = a;
            ws[BN1 + 32 + tid] = b1[tid] - m * a;
        }
    } else {
        int idx = (gid - 1) * 256 + tid;
        if (idx < BATCH * EDIM) ws[Y2OFF + idx] = fcb[idx % EDIM];
    }
}

// k4: FC GEMM  y2[b,j] += sum_k relu(bn1(yc[b,k])) * fcw[j,k]
// 64x64 tile, 4x4/thread, K split 8 ways (576 each), atomic reduce into y2.
__global__ __launch_bounds__(256) void k4_fc(float* __restrict__ ws,
                                             const float* __restrict__ fcw) {
    __shared__ float As[16][68];
    __shared__ float Bs[16][68];
    const float* yc = ws + YCOFF;
    const float* bn1p = ws + BN1;
    float* y2 = ws + Y2OFF;
    int tid = threadIdx.x;
    int tx = tid & 15, ty = tid >> 4;
    int j0 = blockIdx.x * 64;
    int m0 = blockIdx.y * 64;
    int kbase = blockIdx.z * 576;
    float acc[4][4];
    #pragma unroll
    for (int i = 0; i < 4; i++)
        #pragma unroll
        for (int j = 0; j < 4; j++) acc[i][j] = 0.f;

    for (int kc = 0; kc < 576; kc += 16) {
        for (int idx = tid; idx < 1024; idx += 256) {
            int k = idx & 15, mm = idx >> 4;
            int gk = kbase + kc + k;
            int o = gk / 144;
            float v = yc[(size_t)(m0 + mm) * FCK + gk];
            v = fmaf(v, bn1p[o], bn1p[32 + o]);
            As[k][mm] = v > 0.f ? v : 0.f;
        }
        for (int idx = tid; idx < 1024; idx += 256) {
            int k = idx & 15, jj = idx >> 4;
            int gj = j0 + jj;
            Bs[k][jj] = (gj < EDIM) ? fcw[(size_t)gj * FCK + kbase + kc + k] : 0.f;
        }
        __syncthreads();
        #pragma unroll
        for (int kk = 0; kk < 16; kk++) {
            float4 a = *(const float4*)&As[kk][ty * 4];
            float4 b = *(const float4*)&Bs[kk][tx * 4];
            float av[4] = {a.x, a.y, a.z, a.w};
            float bv[4] = {b.x, b.y, b.z, b.w};
            #pragma unroll
            for (int i = 0; i < 4; i++)
                #pragma unroll
                for (int j = 0; j < 4; j++)
                    acc[i][j] = fmaf(av[i], bv[j], acc[i][j]);
        }
        __syncthreads();
    }
    #pragma unroll
    for (int i = 0; i < 4; i++) {
        int m = m0 + ty * 4 + i;
        #pragma unroll
        for (int j = 0; j < 4; j++) {
            int gj = j0 + tx * 4 + j;
            if (gj < EDIM) atomicAdd(&y2[m * EDIM + gj], acc[i][j]);
        }
    }
}

// k5: bn2 per-feature stats over batch -> scale/shift
__global__ __launch_bounds__(256) void k5_bn2(const float* __restrict__ g2,
                                              const float* __restrict__ b2,
                                              float* __restrict__ ws) {
    __shared__ float red[256], red2[256];
    int j = blockIdx.x, tid = threadIdx.x;
    float s = 0.f, s2 = 0.f;
    for (int b = tid; b < BATCH; b += 256) {
        float v = ws[Y2OFF + b * EDIM + j];
        s += v; s2 += v * v;
    }
    red[tid] = s; red2[tid] = s2;
    __syncthreads();
    for (int off = 128; off; off >>= 1) {
        if (tid < off) { red[tid] += red[tid + off]; red2[tid] += red2[tid + off]; }
        __syncthreads();
    }
    if (tid == 0) {
        const float inv = 1.0f / BATCH;
        float m = red[0] * inv;
        float var = red2[0] * inv - m * m;
        float a = rsqrtf(var + EPSV) * g2[j];
        ws[BN2 + j] = a;
        ws[BN2 + EDIM + j] = b2[j] - m * a;
    }
}

// k6: logits = sigmoid( relu(bn2(y2)) @ emb^T + bias_e )
// 128x128 tile, 8x8/thread (split as 2x float4 each dim), K=200 in chunks of 20.
__global__ __launch_bounds__(256) void k6_gemm(const float* __restrict__ ws,
                                               const float* __restrict__ emb,
                                               const float* __restrict__ be,
                                               float* __restrict__ out) {
    __shared__ float As[20][132];
    __shared__ float Bs[20][132];
    const float* y2 = ws + Y2OFF;
    const float* bn2p = ws + BN2;
    int tid = threadIdx.x;
    int tx = tid & 15, ty = tid >> 4;
    int n0 = blockIdx.x * 128;
    int m0 = blockIdx.y * 128;
    float acc[8][8];
    #pragma unroll
    for (int i = 0; i < 8; i++)
        #pragma unroll
        for (int j = 0; j < 8; j++) acc[i][j] = 0.f;

    for (int kc = 0; kc < EDIM; kc += 20) {
        for (int idx = tid; idx < 2560; idx += 256) {
            int k = idx % 20, mm = idx / 20;
            float v = y2[(m0 + mm) * EDIM + kc + k];
            v = fmaf(v, bn2p[kc + k], bn2p[EDIM + kc + k]);
            As[k][mm] = v > 0.f ? v : 0.f;
        }
        for (int idx = tid; idx < 2560; idx += 256) {
            int k = idx % 20, nn = idx / 20;
            int gn = n0 + nn;
            Bs[k][nn] = (gn < NUM_ENT) ? emb[(size_t)gn * EDIM + kc + k] : 0.f;
        }
        __syncthreads();
        #pragma unroll
        for (int kk = 0; kk < 20; kk++) {
            float a[8], b[8];
            *(float4*)&a[0] = *(const float4*)&As[kk][ty * 4];
            *(float4*)&a[4] = *(const float4*)&As[kk][64 + ty * 4];
            *(float4*)&b[0] = *(const float4*)&Bs[kk][tx * 4];
            *(float4*)&b[4] = *(const float4*)&Bs[kk][64 + tx * 4];
            #pragma unroll
            for (int i = 0; i < 8; i++)
                #pragma unroll
                for (int j = 0; j < 8; j++)
                    acc[i][j] = fmaf(a[i], b[j], acc[i][j]);
        }
        __syncthreads();
    }

    int nlo = n0 + tx * 4;
    int nhi = n0 + 64 + tx * 4;
    #pragma unroll
    for (int i = 0; i < 8; i++) {
        int m = m0 + ((i < 4) ? (ty * 4 + i) : (64 + ty * 4 + (i - 4)));
        size_t rowbase = (size_t)m * NUM_ENT;
        if (nlo + 3 < NUM_ENT) {
            float4 v;
            v.x = sigf(acc[i][0] + be[nlo + 0]);
            v.y = sigf(acc[i][1] + be[nlo + 1]);
            v.z = sigf(acc[i][2] + be[nlo + 2]);
            v.w = sigf(acc[i][3] + be[nlo + 3]);
            *(float4*)&out[rowbase + nlo] = v;
        } else {
            #pragma unroll
            for (int j = 0; j < 4; j++) {
                int n = nlo + j;
                if (n < NUM_ENT) out[rowbase + n] = sigf(acc[i][j] + be[n]);
            }
        }
        if (nhi + 3 < NUM_ENT) {
            float4 v;
            v.x = sigf(acc[i][4] + be[nhi + 0]);
            v.y = sigf(acc[i][5] + be[nhi + 1]);
            v.z = sigf(acc[i][6] + be[nhi + 2]);
            v.w = sigf(acc[i][7] + be[nhi + 3]);
            *(float4*)&out[rowbase + nhi] = v;
        } else {
            #pragma unroll
            for (int j = 0; j < 4; j++) {
                int n = nhi + j;
                if (n < NUM_ENT) out[rowbase + n] = sigf(acc[i][4 + j] + be[n]);
            }
        }
    }
}

extern "C" void kernel_launch(void* const* d_in, const int* in_sizes, int n_in,
                              void* d_out, int out_size, void* d_ws, size_t ws_size,
                              hipStream_t stream) {
    const int*   e1  = (const int*)d_in[0];
    const int*   rel = (const int*)d_in[1];
    const float* emb = (const float*)d_in[2];
    const float* cw  = (const float*)d_in[3];
    const float* cb  = (const float*)d_in[4];
    const float* g0  = (const float*)d_in[5];
    const float* b0  = (const float*)d_in[6];
    const float* g1  = (const float*)d_in[7];
    const float* b1  = (const float*)d_in[8];
    const float* g2  = (const float*)d_in[9];
    const float* b2  = (const float*)d_in[10];
    const float* fcw = (const float*)d_in[11];
    const float* fcb = (const float*)d_in[12];
    const float* be  = (const float*)d_in[13];
    float* ws  = (float*)d_ws;
    float* out = (float*)d_out;

    k1_bn0 <<<1, 256, 0, stream>>>(e1, emb, g0, ws);
    k2_conv<<<BATCH, 256, 0, stream>>>(e1, rel, emb, cw, cb, b0, ws);
    k3_prep<<<401, 256, 0, stream>>>(g1, b1, fcb, ws);
    k4_fc  <<<dim3(4, 8, 8), 256, 0, stream>>>(ws, fcw);
    k5_bn2 <<<200, 256, 0, stream>>>(g2, b2, ws);
    k6_gemm<<<dim3(782, 4), 256, 0, stream>>>(ws, emb, be, out);
}

// Round 2
// 872.184 us; speedup vs baseline: 2.4246x; 2.4246x over previous
//
#include <hip/hip_runtime.h>
#include <hip/hip_bf16.h>

// ---------------- problem constants ----------------
#define BATCH   512
#define NUM_ENT 100000
#define EDIM    200
#define OCH     32          // conv out channels
#define OH      8
#define OW      18
#define FCK     4608        // 32*8*18
#define EPSV    1e-5f
#define KSPLIT  4           // k4 K-split factor (K chunk = 1152)

// ---------------- ws layout (floats) ----------------
#define WS0   0        // [2]    bn0: mean, rs*g0
#define BN1   8        // [64]   bn1: scale[32], shift[32]
#define BN2   96       // [400]  bn2: scale[200], shift[200]
#define K1P   512      // [128]  bn0 per-block partials (64 blocks x {sum,sumsq})
#define Y2OFF 1024     // [512*200]
#define YCOFF 103424   // [512*32*8*18] = 2359296
#define PART  2462720  // [KSPLIT*512*200] = 409600 -> ends 2872320 (11.5 MB)

__device__ __forceinline__ float sigf(float x) {
    return 1.0f / (1.0f + __expf(-x));
}

// k1a: bn0 partial sums over gathered embeddings (64 blocks x 1600 elems)
__global__ __launch_bounds__(256) void k1a_bn0(const int* __restrict__ e1,
                                               const float* __restrict__ emb,
                                               float* __restrict__ ws) {
    __shared__ float red[256], red2[256];
    int tid = threadIdx.x;
    int base = blockIdx.x * 1600;
    float s = 0.f, s2 = 0.f;
    for (int i = base + tid; i < base + 1600; i += 256) {
        int b = i / EDIM;
        int k = i - b * EDIM;
        float v = emb[(size_t)e1[b] * EDIM + k];
        s += v; s2 += v * v;
    }
    red[tid] = s; red2[tid] = s2;
    __syncthreads();
    for (int off = 128; off; off >>= 1) {
        if (tid < off) { red[tid] += red[tid + off]; red2[tid] += red2[tid + off]; }
        __syncthreads();
    }
    if (tid == 0) {
        ws[K1P + 2 * blockIdx.x + 0] = red[0];
        ws[K1P + 2 * blockIdx.x + 1] = red2[0];
    }
}

// k1b: finalize bn0
__global__ __launch_bounds__(64) void k1b_bn0(const float* __restrict__ g0,
                                              float* __restrict__ ws) {
    __shared__ float red[64], red2[64];
    int tid = threadIdx.x;
    red[tid]  = ws[K1P + 2 * tid + 0];
    red2[tid] = ws[K1P + 2 * tid + 1];
    __syncthreads();
    for (int off = 32; off; off >>= 1) {
        if (tid < off) { red[tid] += red[tid + off]; red2[tid] += red2[tid + off]; }
        __syncthreads();
    }
    if (tid == 0) {
        const float inv = 1.0f / (BATCH * EDIM);
        float m = red[0] * inv;
        float var = red2[0] * inv - m * m;
        ws[WS0 + 0] = m;
        ws[WS0 + 1] = rsqrtf(var + EPSV) * g0[0];
    }
}

// k2: relation-indexed 3x3 conv on bn0-normalized x (no stats, no atomics)
__global__ __launch_bounds__(256) void k2_conv(const int* __restrict__ e1,
                                               const int* __restrict__ rel,
                                               const float* __restrict__ emb,
                                               const float* __restrict__ cw,
                                               const float* __restrict__ cb,
                                               const float* __restrict__ b0,
                                               float* __restrict__ ws) {
    __shared__ float xs[EDIM];
    __shared__ float wsh[OCH * 9];
    __shared__ float bsh[OCH];
    int b = blockIdx.x, tid = threadIdx.x;
    float m = ws[WS0 + 0], s = ws[WS0 + 1], b0v = b0[0];
    int r = rel[b];
    if (tid < EDIM) xs[tid] = fmaf(emb[(size_t)e1[b] * EDIM + tid] - m, s, b0v);
    for (int i = tid; i < OCH * 9; i += 256) wsh[i] = cw[(size_t)r * OCH * 9 + i];
    if (tid < OCH) bsh[tid] = cb[r * OCH + tid];
    __syncthreads();
    int o = tid >> 3, h = tid & 7;   // 32 channels x 8 rows
    float w0 = wsh[o*9+0], w1 = wsh[o*9+1], w2 = wsh[o*9+2];
    float w3 = wsh[o*9+3], w4 = wsh[o*9+4], w5 = wsh[o*9+5];
    float w6 = wsh[o*9+6], w7 = wsh[o*9+7], w8 = wsh[o*9+8];
    float bias = bsh[o];
    float* yout = ws + YCOFF + ((size_t)b * OCH + o) * (OH * OW) + h * OW;
    const float* r0 = &xs[(h + 0) * 20];
    const float* r1 = &xs[(h + 1) * 20];
    const float* r2 = &xs[(h + 2) * 20];
    #pragma unroll
    for (int wd = 0; wd < OW; wd++) {
        float acc = bias;
        acc = fmaf(r0[wd+0], w0, acc); acc = fmaf(r0[wd+1], w1, acc); acc = fmaf(r0[wd+2], w2, acc);
        acc = fmaf(r1[wd+0], w3, acc); acc = fmaf(r1[wd+1], w4, acc); acc = fmaf(r1[wd+2], w5, acc);
        acc = fmaf(r2[wd+0], w6, acc); acc = fmaf(r2[wd+1], w7, acc); acc = fmaf(r2[wd+2], w8, acc);
        yout[wd] = acc;
    }
}

// k3: bn1 stats from yc — one block per channel, LDS reduce, plain stores
__global__ __launch_bounds__(256) void k3_bn1(const float* __restrict__ g1,
                                              const float* __restrict__ b1,
                                              float* __restrict__ ws) {
    __shared__ float red[256], red2[256];
    int o = blockIdx.x, tid = threadIdx.x;
    const float* yc = ws + YCOFF;
    float s = 0.f, s2 = 0.f;
    for (int idx = tid; idx < BATCH * OH * OW; idx += 256) {
        int b = idx / (OH * OW);
        int p = idx - b * (OH * OW);
        float v = yc[((size_t)b * OCH + o) * (OH * OW) + p];
        s += v; s2 += v * v;
    }
    red[tid] = s; red2[tid] = s2;
    __syncthreads();
    for (int off = 128; off; off >>= 1) {
        if (tid < off) { red[tid] += red[tid + off]; red2[tid] += red2[tid + off]; }
        __syncthreads();
    }
    if (tid == 0) {
        const float inv = 1.0f / (BATCH * OH * OW);
        float m = red[0] * inv;
        float var = red2[0] * inv - m * m;
        float a = rsqrtf(var + EPSV) * g1[o];
        ws[BN1 + o] = a;
        ws[BN1 + 32 + o] = b1[o] - m * a;
    }
}

// k4: FC GEMM partials  part[z][b][j] = sum_{k in chunk z} relu(bn1(yc[b,k])) * fcw[j,k]
// 64x64 tile, 4x4/thread, K split KSPLIT ways (1152 each), plain stores.
__global__ __launch_bounds__(256) void k4_fc(float* __restrict__ ws,
                                             const float* __restrict__ fcw) {
    __shared__ float As[16][68];
    __shared__ float Bs[16][68];
    const float* yc = ws + YCOFF;
    const float* bn1p = ws + BN1;
    int tid = threadIdx.x;
    int tx = tid & 15, ty = tid >> 4;
    int j0 = blockIdx.x * 64;
    int m0 = blockIdx.y * 64;
    int kbase = blockIdx.z * (FCK / KSPLIT);
    float* part = ws + PART + (size_t)blockIdx.z * BATCH * EDIM;
    float acc[4][4];
    #pragma unroll
    for (int i = 0; i < 4; i++)
        #pragma unroll
        for (int j = 0; j < 4; j++) acc[i][j] = 0.f;

    for (int kc = 0; kc < FCK / KSPLIT; kc += 16) {
        for (int idx = tid; idx < 1024; idx += 256) {
            int k = idx & 15, mm = idx >> 4;
            int gk = kbase + kc + k;
            int o = gk / 144;
            float v = yc[(size_t)(m0 + mm) * FCK + gk];
            v = fmaf(v, bn1p[o], bn1p[32 + o]);
            As[k][mm] = v > 0.f ? v : 0.f;
        }
        for (int idx = tid; idx < 1024; idx += 256) {
            int k = idx & 15, jj = idx >> 4;
            int gj = j0 + jj;
            Bs[k][jj] = (gj < EDIM) ? fcw[(size_t)gj * FCK + kbase + kc + k] : 0.f;
        }
        __syncthreads();
        #pragma unroll
        for (int kk = 0; kk < 16; kk++) {
            float4 a = *(const float4*)&As[kk][ty * 4];
            float4 b = *(const float4*)&Bs[kk][tx * 4];
            float av[4] = {a.x, a.y, a.z, a.w};
            float bv[4] = {b.x, b.y, b.z, b.w};
            #pragma unroll
            for (int i = 0; i < 4; i++)
                #pragma unroll
                for (int j = 0; j < 4; j++)
                    acc[i][j] = fmaf(av[i], bv[j], acc[i][j]);
        }
        __syncthreads();
    }
    #pragma unroll
    for (int i = 0; i < 4; i++) {
        int m = m0 + ty * 4 + i;
        #pragma unroll
        for (int j = 0; j < 4; j++) {
            int gj = j0 + tx * 4 + j;
            if (gj < EDIM) part[m * EDIM + gj] = acc[i][j];
        }
    }
}

// k5: y2 = sum_z part[z] + fc_b; bn2 stats -> scale/shift. One block per feature j.
__global__ __launch_bounds__(256) void k5_bn2(const float* __restrict__ g2,
                                              const float* __restrict__ b2,
                                              const float* __restrict__ fcb,
                                              float* __restrict__ ws) {
    __shared__ float red[256], red2[256];
    int j = blockIdx.x, tid = threadIdx.x;
    float* y2 = ws + Y2OFF;
    const float* part = ws + PART;
    float bias = fcb[j];
    float s = 0.f, s2 = 0.f;
    for (int b = tid; b < BATCH; b += 256) {
        float v = bias;
        #pragma unroll
        for (int z = 0; z < KSPLIT; z++)
            v += part[(size_t)z * BATCH * EDIM + b * EDIM + j];
        y2[b * EDIM + j] = v;
        s += v; s2 += v * v;
    }
    red[tid] = s; red2[tid] = s2;
    __syncthreads();
    for (int off = 128; off; off >>= 1) {
        if (tid < off) { red[tid] += red[tid + off]; red2[tid] += red2[tid + off]; }
        __syncthreads();
    }
    if (tid == 0) {
        const float inv = 1.0f / BATCH;
        float m = red[0] * inv;
        float var = red2[0] * inv - m * m;
        float a = rsqrtf(var + EPSV) * g2[j];
        ws[BN2 + j] = a;
        ws[BN2 + EDIM + j] = b2[j] - m * a;
    }
}

// k6: logits = sigmoid( relu(bn2(y2)) @ emb^T + bias_e )
// 128x128 tile, 8x8/thread (split as 2x float4 each dim), K=200 in chunks of 20.
__global__ __launch_bounds__(256) void k6_gemm(const float* __restrict__ ws,
                                               const float* __restrict__ emb,
                                               const float* __restrict__ be,
                                               float* __restrict__ out) {
    __shared__ float As[20][132];
    __shared__ float Bs[20][132];
    const float* y2 = ws + Y2OFF;
    const float* bn2p = ws + BN2;
    int tid = threadIdx.x;
    int tx = tid & 15, ty = tid >> 4;
    int n0 = blockIdx.x * 128;
    int m0 = blockIdx.y * 128;
    float acc[8][8];
    #pragma unroll
    for (int i = 0; i < 8; i++)
        #pragma unroll
        for (int j = 0; j < 8; j++) acc[i][j] = 0.f;

    for (int kc = 0; kc < EDIM; kc += 20) {
        for (int idx = tid; idx < 2560; idx += 256) {
            int k = idx % 20, mm = idx / 20;
            float v = y2[(m0 + mm) * EDIM + kc + k];
            v = fmaf(v, bn2p[kc + k], bn2p[EDIM + kc + k]);
            As[k][mm] = v > 0.f ? v : 0.f;
        }
        for (int idx = tid; idx < 2560; idx += 256) {
            int k = idx % 20, nn = idx / 20;
            int gn = n0 + nn;
            Bs[k][nn] = (gn < NUM_ENT) ? emb[(size_t)gn * EDIM + kc + k] : 0.f;
        }
        __syncthreads();
        #pragma unroll
        for (int kk = 0; kk < 20; kk++) {
            float a[8], b[8];
            *(float4*)&a[0] = *(const float4*)&As[kk][ty * 4];
            *(float4*)&a[4] = *(const float4*)&As[kk][64 + ty * 4];
            *(float4*)&b[0] = *(const float4*)&Bs[kk][tx * 4];
            *(float4*)&b[4] = *(const float4*)&Bs[kk][64 + tx * 4];
            #pragma unroll
            for (int i = 0; i < 8; i++)
                #pragma unroll
                for (int j = 0; j < 8; j++)
                    acc[i][j] = fmaf(a[i], b[j], acc[i][j]);
        }
        __syncthreads();
    }

    int nlo = n0 + tx * 4;
    int nhi = n0 + 64 + tx * 4;
    #pragma unroll
    for (int i = 0; i < 8; i++) {
        int m = m0 + ((i < 4) ? (ty * 4 + i) : (64 + ty * 4 + (i - 4)));
        size_t rowbase = (size_t)m * NUM_ENT;
        if (nlo + 3 < NUM_ENT) {
            float4 v;
            v.x = sigf(acc[i][0] + be[nlo + 0]);
            v.y = sigf(acc[i][1] + be[nlo + 1]);
            v.z = sigf(acc[i][2] + be[nlo + 2]);
            v.w = sigf(acc[i][3] + be[nlo + 3]);
            *(float4*)&out[rowbase + nlo] = v;
        } else {
            #pragma unroll
            for (int j = 0; j < 4; j++) {
                int n = nlo + j;
                if (n < NUM_ENT) out[rowbase + n] = sigf(acc[i][j] + be[n]);
            }
        }
        if (nhi + 3 < NUM_ENT) {
            float4 v;
            v.x = sigf(acc[i][4] + be[nhi + 0]);
            v.y = sigf(acc[i][5] + be[nhi + 1]);
            v.z = sigf(acc[i][6] + be[nhi + 2]);
            v.w = sigf(acc[i][7] + be[nhi + 3]);
            *(float4*)&out[rowbase + nhi] = v;
        } else {
            #pragma unroll
            for (int j = 0; j < 4; j++) {
                int n = nhi + j;
                if (n < NUM_ENT) out[rowbase + n] = sigf(acc[i][4 + j] + be[n]);
            }
        }
    }
}

extern "C" void kernel_launch(void* const* d_in, const int* in_sizes, int n_in,
                              void* d_out, int out_size, void* d_ws, size_t ws_size,
                              hipStream_t stream) {
    const int*   e1  = (const int*)d_in[0];
    const int*   rel = (const int*)d_in[1];
    const float* emb = (const float*)d_in[2];
    const float* cw  = (const float*)d_in[3];
    const float* cb  = (const float*)d_in[4];
    const float* g0  = (const float*)d_in[5];
    const float* b0  = (const float*)d_in[6];
    const float* g1  = (const float*)d_in[7];
    const float* b1  = (const float*)d_in[8];
    const float* g2  = (const float*)d_in[9];
    const float* b2  = (const float*)d_in[10];
    const float* fcw = (const float*)d_in[11];
    const float* fcb = (const float*)d_in[12];
    const float* be  = (const float*)d_in[13];
    float* ws  = (float*)d_ws;
    float* out = (float*)d_out;

    k1a_bn0<<<64, 256, 0, stream>>>(e1, emb, ws);
    k1b_bn0<<<1, 64, 0, stream>>>(g0, ws);
    k2_conv<<<BATCH, 256, 0, stream>>>(e1, rel, emb, cw, cb, b0, ws);
    k3_bn1 <<<OCH, 256, 0, stream>>>(g1, b1, ws);
    k4_fc  <<<dim3(4, 8, KSPLIT), 256, 0, stream>>>(ws, fcw);
    k5_bn2 <<<EDIM, 256, 0, stream>>>(g2, b2, fcb, ws);
    k6_gemm<<<dim3(782, 4), 256, 0, stream>>>(ws, emb, be, out);
}

// Round 3
// 695.683 us; speedup vs baseline: 3.0398x; 1.2537x over previous
//
#include <hip/hip_runtime.h>
#include <hip/hip_bf16.h>

// ---------------- problem constants ----------------
#define BATCH   512
#define NUM_ENT 100000
#define EDIM    200
#define KPAD    224         // EDIM padded to multiple of 32
#define OCH     32          // conv out channels
#define OH      8
#define OW      18
#define FCK     4608        // 32*8*18
#define EPSV    1e-5f
#define KSPLIT  4           // k4 K-split factor (K chunk = 1152)

// ---------------- ws layout (float offsets) ----------------
#define WS0   0        // [2]    bn0: mean, rs*g0
#define BN1   8        // [64]   bn1: scale[32], shift[32]
#define K1P   512      // [128]  bn0 per-block partials
#define K3P   704      // [512]  bn1 per-block partials (256 blocks x {sum,sumsq})
#define YCOFF 2048     // [512*32*8*18] = 2359296 -> ends 2361344
#define PART  2361344  // [KSPLIT*512*200] = 409600 -> ends 2770944 (11.08 MB)
// A hi/lo (bf16) overlap the yc region (yc dead after k4):
#define AHI   2048     // 512*224 ushorts = 57344 floats -> ends 59392
#define ALO   59392    // 512*224 ushorts -> ends 116736 (< PART, no overlap)

typedef short bf16x8 __attribute__((ext_vector_type(8)));
typedef float f32x4  __attribute__((ext_vector_type(4)));

__device__ __forceinline__ float sigf(float x) {
    return 1.0f / (1.0f + __expf(-x));
}

__device__ __forceinline__ unsigned short bf16_rn(float v) {
    unsigned int u = __float_as_uint(v);
    unsigned int r = (u + 0x7FFFu + ((u >> 16) & 1u)) >> 16;
    return (unsigned short)r;
}

__device__ __forceinline__ void split_bf16(float v, unsigned short& hi, unsigned short& lo) {
    hi = bf16_rn(v);
    float hf = __uint_as_float(((unsigned int)hi) << 16);
    lo = bf16_rn(v - hf);
}

// k1a: bn0 partial sums over gathered embeddings
__global__ __launch_bounds__(256) void k1a_bn0(const int* __restrict__ e1,
                                               const float* __restrict__ emb,
                                               float* __restrict__ ws) {
    __shared__ float red[256], red2[256];
    int tid = threadIdx.x;
    int base = blockIdx.x * 1600;
    float s = 0.f, s2 = 0.f;
    for (int i = base + tid; i < base + 1600; i += 256) {
        int b = i / EDIM;
        int k = i - b * EDIM;
        float v = emb[(size_t)e1[b] * EDIM + k];
        s += v; s2 += v * v;
    }
    red[tid] = s; red2[tid] = s2;
    __syncthreads();
    for (int off = 128; off; off >>= 1) {
        if (tid < off) { red[tid] += red[tid + off]; red2[tid] += red2[tid + off]; }
        __syncthreads();
    }
    if (tid == 0) {
        ws[K1P + 2 * blockIdx.x + 0] = red[0];
        ws[K1P + 2 * blockIdx.x + 1] = red2[0];
    }
}

// k1b: finalize bn0
__global__ __launch_bounds__(64) void k1b_bn0(const float* __restrict__ g0,
                                              float* __restrict__ ws) {
    __shared__ float red[64], red2[64];
    int tid = threadIdx.x;
    red[tid]  = ws[K1P + 2 * tid + 0];
    red2[tid] = ws[K1P + 2 * tid + 1];
    __syncthreads();
    for (int off = 32; off; off >>= 1) {
        if (tid < off) { red[tid] += red[tid + off]; red2[tid] += red2[tid + off]; }
        __syncthreads();
    }
    if (tid == 0) {
        const float inv = 1.0f / (BATCH * EDIM);
        float m = red[0] * inv;
        float var = red2[0] * inv - m * m;
        ws[WS0 + 0] = m;
        ws[WS0 + 1] = rsqrtf(var + EPSV) * g0[0];
    }
}

// k2: relation-indexed 3x3 conv on bn0-normalized x
__global__ __launch_bounds__(256) void k2_conv(const int* __restrict__ e1,
                                               const int* __restrict__ rel,
                                               const float* __restrict__ emb,
                                               const float* __restrict__ cw,
                                               const float* __restrict__ cb,
                                               const float* __restrict__ b0,
                                               float* __restrict__ ws) {
    __shared__ float xs[EDIM];
    __shared__ float wsh[OCH * 9];
    __shared__ float bsh[OCH];
    int b = blockIdx.x, tid = threadIdx.x;
    float m = ws[WS0 + 0], s = ws[WS0 + 1], b0v = b0[0];
    int r = rel[b];
    if (tid < EDIM) xs[tid] = fmaf(emb[(size_t)e1[b] * EDIM + tid] - m, s, b0v);
    for (int i = tid; i < OCH * 9; i += 256) wsh[i] = cw[(size_t)r * OCH * 9 + i];
    if (tid < OCH) bsh[tid] = cb[r * OCH + tid];
    __syncthreads();
    int o = tid >> 3, h = tid & 7;
    float w0 = wsh[o*9+0], w1 = wsh[o*9+1], w2 = wsh[o*9+2];
    float w3 = wsh[o*9+3], w4 = wsh[o*9+4], w5 = wsh[o*9+5];
    float w6 = wsh[o*9+6], w7 = wsh[o*9+7], w8 = wsh[o*9+8];
    float bias = bsh[o];
    float* yout = ws + YCOFF + ((size_t)b * OCH + o) * (OH * OW) + h * OW;
    const float* r0 = &xs[(h + 0) * 20];
    const float* r1 = &xs[(h + 1) * 20];
    const float* r2 = &xs[(h + 2) * 20];
    #pragma unroll
    for (int wd = 0; wd < OW; wd++) {
        float acc = bias;
        acc = fmaf(r0[wd+0], w0, acc); acc = fmaf(r0[wd+1], w1, acc); acc = fmaf(r0[wd+2], w2, acc);
        acc = fmaf(r1[wd+0], w3, acc); acc = fmaf(r1[wd+1], w4, acc); acc = fmaf(r1[wd+2], w5, acc);
        acc = fmaf(r2[wd+0], w6, acc); acc = fmaf(r2[wd+1], w7, acc); acc = fmaf(r2[wd+2], w8, acc);
        yout[wd] = acc;
    }
}

// k3a: bn1 partial stats — 8 slices per channel, 256 blocks
__global__ __launch_bounds__(256) void k3a_bn1(float* __restrict__ ws) {
    __shared__ float red[256], red2[256];
    int o = blockIdx.x >> 3, sl = blockIdx.x & 7;
    int tid = threadIdx.x;
    const float* yc = ws + YCOFF;
    const int per = (BATCH * OH * OW) / 8;   // 9216
    float s = 0.f, s2 = 0.f;
    for (int i = sl * per + tid; i < (sl + 1) * per; i += 256) {
        int b = i / (OH * OW);
        int p = i - b * (OH * OW);
        float v = yc[((size_t)b * OCH + o) * (OH * OW) + p];
        s += v; s2 += v * v;
    }
    red[tid] = s; red2[tid] = s2;
    __syncthreads();
    for (int off = 128; off; off >>= 1) {
        if (tid < off) { red[tid] += red[tid + off]; red2[tid] += red2[tid + off]; }
        __syncthreads();
    }
    if (tid == 0) {
        ws[K3P + 2 * blockIdx.x + 0] = red[0];
        ws[K3P + 2 * blockIdx.x + 1] = red2[0];
    }
}

// k3b: finalize bn1 -> scale/shift
__global__ __launch_bounds__(256) void k3b_bn1(const float* __restrict__ g1,
                                               const float* __restrict__ b1,
                                               float* __restrict__ ws) {
    __shared__ float rs[256], rq[256];
    int tid = threadIdx.x;
    rs[tid] = ws[K3P + 2 * tid + 0];
    rq[tid] = ws[K3P + 2 * tid + 1];
    __syncthreads();
    if (tid < OCH) {
        float sm = 0.f, sq = 0.f;
        #pragma unroll
        for (int sl = 0; sl < 8; sl++) { sm += rs[tid * 8 + sl]; sq += rq[tid * 8 + sl]; }
        const float inv = 1.0f / (BATCH * OH * OW);
        float m = sm * inv;
        float var = sq * inv - m * m;
        float a = rsqrtf(var + EPSV) * g1[tid];
        ws[BN1 + tid] = a;
        ws[BN1 + 32 + tid] = b1[tid] - m * a;
    }
}

// k4: FC GEMM partials (fp32, 64x64 tile, 4x4/thread, K-split)
__global__ __launch_bounds__(256) void k4_fc(float* __restrict__ ws,
                                             const float* __restrict__ fcw) {
    __shared__ float As[16][68];
    __shared__ float Bs[16][68];
    const float* yc = ws + YCOFF;
    const float* bn1p = ws + BN1;
    int tid = threadIdx.x;
    int tx = tid & 15, ty = tid >> 4;
    int j0 = blockIdx.x * 64;
    int m0 = blockIdx.y * 64;
    int kbase = blockIdx.z * (FCK / KSPLIT);
    float* part = ws + PART + (size_t)blockIdx.z * BATCH * EDIM;
    float acc[4][4];
    #pragma unroll
    for (int i = 0; i < 4; i++)
        #pragma unroll
        for (int j = 0; j < 4; j++) acc[i][j] = 0.f;

    for (int kc = 0; kc < FCK / KSPLIT; kc += 16) {
        for (int idx = tid; idx < 1024; idx += 256) {
            int k = idx & 15, mm = idx >> 4;
            int gk = kbase + kc + k;
            int o = gk / 144;
            float v = yc[(size_t)(m0 + mm) * FCK + gk];
            v = fmaf(v, bn1p[o], bn1p[32 + o]);
            As[k][mm] = v > 0.f ? v : 0.f;
        }
        for (int idx = tid; idx < 1024; idx += 256) {
            int k = idx & 15, jj = idx >> 4;
            int gj = j0 + jj;
            Bs[k][jj] = (gj < EDIM) ? fcw[(size_t)gj * FCK + kbase + kc + k] : 0.f;
        }
        __syncthreads();
        #pragma unroll
        for (int kk = 0; kk < 16; kk++) {
            float4 a = *(const float4*)&As[kk][ty * 4];
            float4 b = *(const float4*)&Bs[kk][tx * 4];
            float av[4] = {a.x, a.y, a.z, a.w};
            float bv[4] = {b.x, b.y, b.z, b.w};
            #pragma unroll
            for (int i = 0; i < 4; i++)
                #pragma unroll
                for (int j = 0; j < 4; j++)
                    acc[i][j] = fmaf(av[i], bv[j], acc[i][j]);
        }
        __syncthreads();
    }
    #pragma unroll
    for (int i = 0; i < 4; i++) {
        int m = m0 + ty * 4 + i;
        #pragma unroll
        for (int j = 0; j < 4; j++) {
            int gj = j0 + tx * 4 + j;
            if (gj < EDIM) part[m * EDIM + gj] = acc[i][j];
        }
    }
}

// k5: y2 = sum_z part + fc_b; bn2; A = relu(bn2(y2)) split to bf16 hi/lo [512][224]
__global__ __launch_bounds__(256) void k5_bn2(const float* __restrict__ g2,
                                              const float* __restrict__ b2,
                                              const float* __restrict__ fcb,
                                              float* __restrict__ ws) {
    unsigned short* gAh = (unsigned short*)(ws + AHI);
    unsigned short* gAl = (unsigned short*)(ws + ALO);
    int j = blockIdx.x, tid = threadIdx.x;
    if (j >= EDIM) {   // zero padding columns 200..223
        for (int b = tid; b < BATCH; b += 256) {
            gAh[(size_t)b * KPAD + j] = 0;
            gAl[(size_t)b * KPAD + j] = 0;
        }
        return;
    }
    __shared__ float red[256], red2[256];
    __shared__ float ss[2];
    const float* part = ws + PART;
    float bias = fcb[j];
    float v0 = bias, v1 = bias;
    #pragma unroll
    for (int z = 0; z < KSPLIT; z++) {
        v0 += part[(size_t)z * BATCH * EDIM + tid * EDIM + j];
        v1 += part[(size_t)z * BATCH * EDIM + (tid + 256) * EDIM + j];
    }
    red[tid] = v0 + v1; red2[tid] = v0 * v0 + v1 * v1;
    __syncthreads();
    for (int off = 128; off; off >>= 1) {
        if (tid < off) { red[tid] += red[tid + off]; red2[tid] += red2[tid + off]; }
        __syncthreads();
    }
    if (tid == 0) {
        const float inv = 1.0f / BATCH;
        float m = red[0] * inv;
        float var = red2[0] * inv - m * m;
        float a = rsqrtf(var + EPSV) * g2[j];
        ss[0] = a;
        ss[1] = b2[j] - m * a;
    }
    __syncthreads();
    float a = ss[0], s = ss[1];
    float r0 = fmaf(v0, a, s); r0 = r0 > 0.f ? r0 : 0.f;
    float r1 = fmaf(v1, a, s); r1 = r1 > 0.f ? r1 : 0.f;
    unsigned short h, l;
    split_bf16(r0, h, l);
    gAh[(size_t)tid * KPAD + j] = h;  gAl[(size_t)tid * KPAD + j] = l;
    split_bf16(r1, h, l);
    gAh[(size_t)(tid + 256) * KPAD + j] = h;  gAl[(size_t)(tid + 256) * KPAD + j] = l;
}

// k6: logits = sigmoid( A @ emb^T + bias_e ), split-bf16 3-pass MFMA.
// 128x128 block tile, 4 waves x (64x64), mfma_f32_16x16x32_bf16.
// LDS in frag-order: per 64-row half, chunk (subtile i, quad q) at
// ushort addr = half*2048 + ((i*4+q)*16 + col)*8  (lane-linear 16B reads).
__global__ __launch_bounds__(256) void k6_gemm(const float* __restrict__ ws,
                                               const float* __restrict__ emb,
                                               const float* __restrict__ be,
                                               float* __restrict__ out) {
    __shared__ unsigned short Ah[4096], Al[4096], Bh[4096], Bl[4096];
    const unsigned short* gAh = (const unsigned short*)(ws + AHI);
    const unsigned short* gAl = (const unsigned short*)(ws + ALO);
    int tid = threadIdx.x;
    int bid = blockIdx.x;
    int m0 = (bid & 3) * 128;          // m fastest: 4 m-blocks share a B-tile in L2
    int n0 = (bid >> 2) * 128;
    int lane = tid & 63, wave = tid >> 6;
    int col = lane & 15, quad = lane >> 4;
    int mhalf = wave & 1, nhalf = wave >> 1;

    f32x4 acc[4][4];
    #pragma unroll
    for (int i = 0; i < 4; i++)
        #pragma unroll
        for (int j = 0; j < 4; j++)
            acc[i][j] = (f32x4){0.f, 0.f, 0.f, 0.f};

    for (int kc = 0; kc < KPAD; kc += 32) {
        // ---- stage A hi/lo: 128 rows x 32 k (bf16 source, zero-padded) ----
        for (int idx = tid; idx < 512; idx += 256) {
            int r = idx >> 2, c = idx & 3;          // c = quad (8 ushorts)
            int rr = r & 63, half = r >> 6;
            int la = half * 2048 + (((rr >> 4) * 4 + c) * 16 + (rr & 15)) * 8;
            size_t ga = (size_t)(m0 + r) * KPAD + kc + c * 8;
            *(uint4*)&Ah[la] = *(const uint4*)&gAh[ga];
            *(uint4*)&Al[la] = *(const uint4*)&gAl[ga];
        }
        // ---- stage B: 128 ent rows x 32 k from emb fp32, split on the fly ----
        for (int idx = tid; idx < 1024; idx += 256) {
            int r = idx >> 3, c = idx & 7;          // c = float4 group (k = c*4)
            int rr = r & 63, half = r >> 6;
            int gn = n0 + r;
            int k = kc + c * 4;
            float4 v = {0.f, 0.f, 0.f, 0.f};
            if (gn < NUM_ENT) {
                if (k + 3 < EDIM) {
                    v = *(const float4*)&emb[(size_t)gn * EDIM + k];
                } else {
                    const float* row = &emb[(size_t)gn * EDIM];
                    v.x = (k + 0 < EDIM) ? row[k + 0] : 0.f;
                    v.y = (k + 1 < EDIM) ? row[k + 1] : 0.f;
                    v.z = (k + 2 < EDIM) ? row[k + 2] : 0.f;
                    v.w = (k + 3 < EDIM) ? row[k + 3] : 0.f;
                }
            }
            ushort4 hs, ls;
            split_bf16(v.x, hs.x, ls.x);
            split_bf16(v.y, hs.y, ls.y);
            split_bf16(v.z, hs.z, ls.z);
            split_bf16(v.w, hs.w, ls.w);
            int la = half * 2048 + (((rr >> 4) * 4 + (c >> 1)) * 16 + (rr & 15)) * 8 + (c & 1) * 4;
            *(ushort4*)&Bh[la] = hs;
            *(ushort4*)&Bl[la] = ls;
        }
        __syncthreads();
        // ---- fragments (lane-linear, conflict-free) ----
        bf16x8 ah[4], al[4], bh[4], bl[4];
        #pragma unroll
        for (int i = 0; i < 4; i++) {
            int base = (i * 4 + quad) * 16 + col;
            ah[i] = *(const bf16x8*)&Ah[mhalf * 2048 + base * 8];
            al[i] = *(const bf16x8*)&Al[mhalf * 2048 + base * 8];
            bh[i] = *(const bf16x8*)&Bh[nhalf * 2048 + base * 8];
            bl[i] = *(const bf16x8*)&Bl[nhalf * 2048 + base * 8];
        }
        #pragma unroll
        for (int i = 0; i < 4; i++)
            #pragma unroll
            for (int j = 0; j < 4; j++) {
                acc[i][j] = __builtin_amdgcn_mfma_f32_16x16x32_bf16(ah[i], bh[j], acc[i][j], 0, 0, 0);
                acc[i][j] = __builtin_amdgcn_mfma_f32_16x16x32_bf16(ah[i], bl[j], acc[i][j], 0, 0, 0);
                acc[i][j] = __builtin_amdgcn_mfma_f32_16x16x32_bf16(al[i], bh[j], acc[i][j], 0, 0, 0);
            }
        __syncthreads();
    }

    // ---- epilogue: C row = quad*4+reg, col = lane&15 ----
    int mw = mhalf * 64, nw = nhalf * 64;
    #pragma unroll
    for (int j = 0; j < 4; j++) {
        int n = n0 + nw + j * 16 + col;
        if (n < NUM_ENT) {
            float bv = be[n];
            #pragma unroll
            for (int i = 0; i < 4; i++) {
                int mbase = m0 + mw + i * 16 + quad * 4;
                #pragma unroll
                for (int r = 0; r < 4; r++)
                    out[(size_t)(mbase + r) * NUM_ENT + n] = sigf(acc[i][j][r] + bv);
            }
        }
    }
}

extern "C" void kernel_launch(void* const* d_in, const int* in_sizes, int n_in,
                              void* d_out, int out_size, void* d_ws, size_t ws_size,
                              hipStream_t stream) {
    const int*   e1  = (const int*)d_in[0];
    const int*   rel = (const int*)d_in[1];
    const float* emb = (const float*)d_in[2];
    const float* cw  = (const float*)d_in[3];
    const float* cb  = (const float*)d_in[4];
    const float* g0  = (const float*)d_in[5];
    const float* b0  = (const float*)d_in[6];
    const float* g1  = (const float*)d_in[7];
    const float* b1  = (const float*)d_in[8];
    const float* g2  = (const float*)d_in[9];
    const float* b2  = (const float*)d_in[10];
    const float* fcw = (const float*)d_in[11];
    const float* fcb = (const float*)d_in[12];
    const float* be  = (const float*)d_in[13];
    float* ws  = (float*)d_ws;
    float* out = (float*)d_out;

    k1a_bn0<<<64, 256, 0, stream>>>(e1, emb, ws);
    k1b_bn0<<<1, 64, 0, stream>>>(g0, ws);
    k2_conv<<<BATCH, 256, 0, stream>>>(e1, rel, emb, cw, cb, b0, ws);
    k3a_bn1<<<256, 256, 0, stream>>>(ws);
    k3b_bn1<<<1, 256, 0, stream>>>(g1, b1, ws);
    k4_fc  <<<dim3(4, 8, KSPLIT), 256, 0, stream>>>(ws, fcw);
    k5_bn2 <<<KPAD, 256, 0, stream>>>(g2, b2, fcb, ws);
    k6_gemm<<<782 * 4, 256, 0, stream>>>(ws, emb, be, out);
}